// Round 11
// baseline (18034.427 us; speedup 1.0000x reference)
//
#include <hip/hip_runtime.h>

#define T_TOK 1024
#define HD    2048
#define NE    64
#define ID    768
#define TOPK  8

typedef __bf16 bf16x8 __attribute__((ext_vector_type(8)));
typedef __bf16 bf16x4 __attribute__((ext_vector_type(4)));
typedef float  f32x4  __attribute__((ext_vector_type(4)));

#define LGKM0  asm volatile("s_waitcnt lgkmcnt(0)" ::: "memory")
#define VMC(N) asm volatile("s_waitcnt vmcnt(" N ")" ::: "memory")
#define BAR()  __builtin_amdgcn_s_barrier()
#define SCHED0 __builtin_amdgcn_sched_barrier(0)
#define FENCE  asm volatile("" ::: "memory")

__device__ __forceinline__ void load_lds16(const void* src, void* lds) {
  __builtin_amdgcn_global_load_lds(
      (const __attribute__((address_space(1))) void*)src,
      (__attribute__((address_space(3))) void*)lds, 16, 0, 0);
}

// ---------------------------------------------------------------------------
// Router: fp64 logits -> top-8 -> renormalized weights; per-expert lists;
// x -> bf16.
// ---------------------------------------------------------------------------
__global__ __launch_bounds__(256) void router_kernel(
    const float* __restrict__ x, const float* __restrict__ rw,
    unsigned short* __restrict__ xb_u, float* __restrict__ tw,
    int* __restrict__ counts, int* __restrict__ lists)
{
  __shared__ float  sx[HD];
  __shared__ double slog[NE];
  const int t = blockIdx.x;
  const int tid = threadIdx.x;
  __bf16* xb = (__bf16*)xb_u;

  for (int i = tid; i < HD; i += 256) {
    float v = x[(size_t)t * HD + i];
    sx[i] = v;
    xb[(size_t)t * HD + i] = (__bf16)v;
  }
  __syncthreads();

  const int e = tid >> 2, p = tid & 3;
  const float* rwrow = rw + (size_t)e * HD;
  double acc = 0.0;
  for (int k = p; k < HD; k += 4)
    acc += (double)sx[k] * (double)rwrow[k];
  acc += __shfl_xor(acc, 1, 64);
  acc += __shfl_xor(acc, 2, 64);
  if (p == 0) slog[e] = acc;
  __syncthreads();

  if (tid < 64) {
    double v = slog[tid];
    double selv = -1e300; int seli = 0; double gmax = 0.0;
    #pragma unroll
    for (int k = 0; k < TOPK; ++k) {
      double bv = v; int bi = tid;
      #pragma unroll
      for (int off = 32; off >= 1; off >>= 1) {
        double ov = __shfl_xor(bv, off, 64);
        int    oi = __shfl_xor(bi, off, 64);
        if (ov > bv || (ov == bv && oi < bi)) { bv = ov; bi = oi; }
      }
      if (k == 0) gmax = bv;
      if (tid == k) { selv = bv; seli = bi; }
      if (tid == bi) v = -1e300;
    }
    double e_ = (tid < TOPK) ? exp(selv - gmax) : 0.0;
    double s = e_;
    #pragma unroll
    for (int off = 32; off >= 1; off >>= 1) s += __shfl_xor(s, off, 64);
    if (tid < TOPK) {
      int slot = t * TOPK + tid;
      tw[slot] = (float)(e_ / s);
      int pos = atomicAdd(&counts[seli], 1);
      lists[seli * T_TOK + pos] = slot;
    }
  }
}

// ---------------------------------------------------------------------------
// GEMM1: block = (expert, 64 i-cols). BM=256 (one pass), BK=32, 64 bodies.
// W loads: 2 instructions/body/wave, each 8 rows x 128-B CONTIGUOUS per row
// (full cache lines). W staged fp32->bf16 via double-buffered sW (write
// pre-barrier, read post-barrier). A via global_load_lds into dbuf sA,
// issued post-compute. One barrier per body; W(t+1) rides through every
// barrier (vmcnt(2)). Wave = 128M x 16N with BOTH gate+up frags in-wave.
// LDS 49 KB, launch_bounds(512,2) -> 2 blocks/CU.
// ---------------------------------------------------------------------------
__global__ __launch_bounds__(512, 2) void gemm1_kernel(
    const unsigned short* __restrict__ xb_u,
    const float* __restrict__ gw, const float* __restrict__ uw,
    const int* __restrict__ counts, const int* __restrict__ lists,
    unsigned short* __restrict__ hb_u)
{
  __shared__ __bf16 sA[2][8192];   // 2 x 256x32 bf16 = 2 x 16 KB
  __shared__ __bf16 sW[2][4096];   // 2 x 128x32 bf16 = 2 x  8 KB
  __shared__ int    sSlot[256];

  const char* xbp = (const char*)xb_u;
  __bf16* hb = (__bf16*)hb_u;

  // 768 blocks = 8 XCD chunks of 96 (12 n-tiles x 8 experts)
  const int wg  = blockIdx.x;
  const int idx = wg >> 3;
  const int e   = (wg & 7) * 8 + idx / 12;
  const int n0  = (idx % 12) * 64;
  const int tid = threadIdx.x, wid = tid >> 6, lane = tid & 63;
  const int mr = wid >> 2, nc = wid & 3;
  const int n_e = counts[e];

  // W global lane addrs: waves 0-3 gate rows, 4-7 up rows; 8 rows x 128 B per
  // instruction (row = lane>>3, 16-B chunk = lane&7). Per-body offset 128 B.
  const char* wmat = (const char*)((wid < 4) ? gw : uw);
  const char* wl0 = wmat
      + ((size_t)e * ID + n0 + (wid & 3) * 16 + (lane >> 3)) * (size_t)(HD * 4)
      + (size_t)(lane & 7) * 16;
  const char* wl1 = wl0 + (size_t)8 * (HD * 4);

  // W LDS write offsets (bf16x4 = 8 B per lane per instruction)
  const int wr0 = wid * 16 + (lane >> 3), wr1 = wr0 + 8, kc = lane & 7;
  const int wd0 = wr0 * 64 + (((kc >> 1) ^ (wr0 & 3)) << 4) + (kc & 1) * 8;
  const int wd1 = wr1 * 64 + (((kc >> 1) ^ (wr1 & 3)) << 4) + (kc & 1) * 8;

  // frag offsets
  const int q = lane >> 4;
  int afo[8];
  #pragma unroll
  for (int m = 0; m < 8; ++m) {
    int r = mr * 128 + m * 16 + (lane & 15);
    afo[m] = r * 64 + ((q ^ (r & 3)) << 4);
  }
  const int rg  = nc * 16 + (lane & 15);
  const int wgo = rg * 64 + ((q ^ (rg & 3)) << 4);
  const int wuo = (rg + 64) * 64 + ((q ^ (rg & 3)) << 4);

#define G1BODY(BUF, CW0, CW1, NW0, NW1, DOW, DOA, VML, TNXT)                    \
  {                                                                             \
    bf16x4 c0_, c1_;                                                            \
    _Pragma("unroll") for (int z = 0; z < 4; ++z) {                             \
      c0_[z] = (__bf16)CW0[z]; c1_[z] = (__bf16)CW1[z];                         \
    }                                                                           \
    *(bf16x4*)((char*)&sW[BUF][0] + wd0) = c0_;                                 \
    *(bf16x4*)((char*)&sW[BUF][0] + wd1) = c1_;                                 \
    if (DOW) {                                                                  \
      NW0 = *(const f32x4*)(wl0 + (size_t)(TNXT) * 128);                        \
      NW1 = *(const f32x4*)(wl1 + (size_t)(TNXT) * 128);                        \
    }                                                                           \
    FENCE; LGKM0; VMC(VML); BAR(); SCHED0;                                      \
    {                                                                           \
      const char* ab_ = (const char*)&sA[BUF][0];                               \
      const char* wb_ = (const char*)&sW[BUF][0];                               \
      bf16x8 gF_ = *(const bf16x8*)(wb_ + wgo);                                 \
      bf16x8 uF_ = *(const bf16x8*)(wb_ + wuo);                                 \
      _Pragma("unroll") for (int m = 0; m < 8; ++m) if (m * 16 < rem) {         \
        bf16x8 aF_ = *(const bf16x8*)(ab_ + afo[m]);                            \
        accg[m] = __builtin_amdgcn_mfma_f32_16x16x32_bf16(aF_, gF_, accg[m], 0, 0, 0); \
        accu[m] = __builtin_amdgcn_mfma_f32_16x16x32_bf16(aF_, uF_, accu[m], 0, 0, 0); \
      }                                                                         \
    }                                                                           \
    if (DOA) {                                                                  \
      char* d_ = (char*)&sA[1 - (BUF)][0] + wid * 2048 + lane * 16;             \
      load_lds16(aS0 + (size_t)(TNXT) * 64, d_);                                \
      load_lds16(aS1 + (size_t)(TNXT) * 64, d_ + 1024);                         \
    }                                                                           \
    FENCE;                                                                      \
  }

  for (int m0 = 0; m0 < n_e; m0 += 256) {
    __syncthreads();
    sSlot[tid & 255] = (m0 + (tid & 255) < n_e) ? lists[e * T_TOK + m0 + (tid & 255)] : 0;
    __syncthreads();
    const int rem0 = n_e - m0;
    const int rem  = (rem0 - mr * 128 < 128) ? (rem0 - mr * 128) : 128;  // wave-uniform

    // A source bases (pre-swizzled chunk -> linear DMA dst)
    const int r0 = wid * 32 + (lane >> 2), r1 = r0 + 16;
    const char* aS0 = xbp + (size_t)(sSlot[r0 & 255] >> 3) * 4096
                    + (((lane & 3) ^ (r0 & 3)) << 4);
    const char* aS1 = xbp + (size_t)(sSlot[r1 & 255] >> 3) * 4096
                    + (((lane & 3) ^ (r1 & 3)) << 4);

    f32x4 accg[8], accu[8];
    #pragma unroll
    for (int m = 0; m < 8; ++m) {
      accg[m] = (f32x4){0.f, 0.f, 0.f, 0.f};
      accu[m] = (f32x4){0.f, 0.f, 0.f, 0.f};
    }
    f32x4 wa0, wa1, wb0, wb1;

    // prologue: A(0) -> sA[0]; W(0) -> set A
    {
      char* d_ = (char*)&sA[0][0] + wid * 2048 + lane * 16;
      load_lds16(aS0, d_);
      load_lds16(aS1, d_ + 1024);
    }
    wa0 = *(const f32x4*)(wl0);
    wa1 = *(const f32x4*)(wl1);
    FENCE;

    #pragma unroll 1
    for (int it = 0; it < 31; ++it) {               // bodies 0..61
      G1BODY(0, wa0, wa1, wb0, wb1, 1, 1, "2", 2 * it + 1)
      G1BODY(1, wb0, wb1, wa0, wa1, 1, 1, "2", 2 * it + 2)
    }
    G1BODY(0, wa0, wa1, wb0, wb1, 1, 1, "2", 63)    // body 62
    G1BODY(1, wb0, wb1, wa0, wa1, 0, 0, "0", 0)     // body 63

    // epilogue: silu(g)*u -> bf16 hidden_buf (all in-wave)
    #pragma unroll
    for (int m = 0; m < 8; ++m) if (m * 16 < rem) {
      #pragma unroll
      for (int j = 0; j < 4; ++j) {
        int row = mr * 128 + m * 16 + (lane >> 4) * 4 + j;
        if (row < rem0) {
          int s = sSlot[row & 255];
          float gv = accg[m][j], uv = accu[m][j];
          float hv = (gv / (1.0f + expf(-gv))) * uv;
          hb[(size_t)s * ID + (size_t)(n0 + nc * 16 + (lane & 15))] = (__bf16)hv;
        }
      }
    }
  }
#undef G1BODY
}

// ---------------------------------------------------------------------------
// GEMM2: block = (expert, 64 H-cols). BM=256, BK=32, K=768 (24 bodies).
// Same pipeline (1 W instruction/body/wave: 8 rows x 128-B contiguous).
// Weighted atomic scatter to out. LDS 41 KB, 2 blocks/CU.
// ---------------------------------------------------------------------------
__global__ __launch_bounds__(512, 2) void gemm2_kernel(
    const unsigned short* __restrict__ hb_u,
    const float* __restrict__ dw,
    const int* __restrict__ counts, const int* __restrict__ lists,
    const float* __restrict__ tw,
    float* __restrict__ out)
{
  __shared__ __bf16 sA[2][8192];   // 2 x 256x32
  __shared__ __bf16 sW[2][2048];   // 2 x  64x32
  __shared__ int    sSlot[256];

  const char* hbp = (const char*)hb_u;

  // 2048 blocks = 8 XCD chunks of 256 (32 n-tiles x 8 experts)
  const int wg  = blockIdx.x;
  const int idx = wg >> 3;
  const int e   = (wg & 7) * 8 + idx / 32;
  const int n0  = (idx % 32) * 64;
  const int tid = threadIdx.x, wid = tid >> 6, lane = tid & 63;
  const int mr = wid >> 2, nc = wid & 3;
  const int n_e = counts[e];

  // W: wave stages 8 rows (wid*8 + lane>>3), 128-B contiguous per row
  const char* wl0 = (const char*)dw
      + ((size_t)e * HD + n0 + wid * 8 + (lane >> 3)) * (size_t)(ID * 4)
      + (size_t)(lane & 7) * 16;

  const int wr0 = wid * 8 + (lane >> 3), kc = lane & 7;
  const int wd0 = wr0 * 64 + (((kc >> 1) ^ (wr0 & 3)) << 4) + (kc & 1) * 8;

  const int q = lane >> 4;
  int afo[8];
  #pragma unroll
  for (int m = 0; m < 8; ++m) {
    int r = mr * 128 + m * 16 + (lane & 15);
    afo[m] = r * 64 + ((q ^ (r & 3)) << 4);
  }
  const int rd  = nc * 16 + (lane & 15);
  const int wdo = rd * 64 + ((q ^ (rd & 3)) << 4);

#define G2BODY(BUF, CW0, NW0, DOW, DOA, VML, TNXT)                              \
  {                                                                             \
    bf16x4 c0_;                                                                 \
    _Pragma("unroll") for (int z = 0; z < 4; ++z) c0_[z] = (__bf16)CW0[z];      \
    *(bf16x4*)((char*)&sW[BUF][0] + wd0) = c0_;                                 \
    if (DOW) NW0 = *(const f32x4*)(wl0 + (size_t)(TNXT) * 128);                 \
    FENCE; LGKM0; VMC(VML); BAR(); SCHED0;                                      \
    {                                                                           \
      const char* ab_ = (const char*)&sA[BUF][0];                               \
      bf16x8 dF_ = *(const bf16x8*)((const char*)&sW[BUF][0] + wdo);            \
      _Pragma("unroll") for (int m = 0; m < 8; ++m) if (m * 16 < rem) {         \
        bf16x8 aF_ = *(const bf16x8*)(ab_ + afo[m]);                            \
        acc[m] = __builtin_amdgcn_mfma_f32_16x16x32_bf16(aF_, dF_, acc[m], 0, 0, 0); \
      }                                                                         \
    }                                                                           \
    if (DOA) {                                                                  \
      char* d_ = (char*)&sA[1 - (BUF)][0] + wid * 2048 + lane * 16;             \
      load_lds16(aS0 + (size_t)(TNXT) * 64, d_);                                \
      load_lds16(aS1 + (size_t)(TNXT) * 64, d_ + 1024);                         \
    }                                                                           \
    FENCE;                                                                      \
  }

  for (int m0 = 0; m0 < n_e; m0 += 256) {
    __syncthreads();
    sSlot[tid & 255] = (m0 + (tid & 255) < n_e) ? lists[e * T_TOK + m0 + (tid & 255)] : 0;
    __syncthreads();
    const int rem0 = n_e - m0;
    const int rem  = (rem0 - mr * 128 < 128) ? (rem0 - mr * 128) : 128;

    const int r0 = wid * 32 + (lane >> 2), r1 = r0 + 16;
    const char* aS0 = hbp + (size_t)sSlot[r0 & 255] * 1536
                    + (((lane & 3) ^ (r0 & 3)) << 4);
    const char* aS1 = hbp + (size_t)sSlot[r1 & 255] * 1536
                    + (((lane & 3) ^ (r1 & 3)) << 4);

    f32x4 acc[8];
    #pragma unroll
    for (int m = 0; m < 8; ++m) acc[m] = (f32x4){0.f, 0.f, 0.f, 0.f};
    f32x4 wa0, wb0;

    {
      char* d_ = (char*)&sA[0][0] + wid * 2048 + lane * 16;
      load_lds16(aS0, d_);
      load_lds16(aS1, d_ + 1024);
    }
    wa0 = *(const f32x4*)(wl0);
    FENCE;

    #pragma unroll 1
    for (int it = 0; it < 11; ++it) {               // bodies 0..21
      G2BODY(0, wa0, wb0, 1, 1, "1", 2 * it + 1)
      G2BODY(1, wb0, wa0, 1, 1, "1", 2 * it + 2)
    }
    G2BODY(0, wa0, wb0, 1, 1, "1", 23)              // body 22
    G2BODY(1, wb0, wa0, 0, 0, "0", 0)               // body 23

    // epilogue: weighted atomic scatter
    #pragma unroll
    for (int m = 0; m < 8; ++m) if (m * 16 < rem) {
      #pragma unroll
      for (int j = 0; j < 4; ++j) {
        int row = mr * 128 + m * 16 + (lane >> 4) * 4 + j;
        if (row < rem0) {
          int s = sSlot[row & 255];
          float w = tw[s];
          atomicAdd(out + (size_t)(s >> 3) * HD + (size_t)(n0 + nc * 16 + (lane & 15)),
                    w * acc[m][j]);
        }
      }
    }
  }
#undef G2BODY
}

// ---------------------------------------------------------------------------
// Launcher. ws: xb bf16 | tw | counts | lists | hidden_buf bf16 (~17 MB).
// ---------------------------------------------------------------------------
extern "C" void kernel_launch(void* const* d_in, const int* in_sizes, int n_in,
                              void* d_out, int out_size, void* d_ws, size_t ws_size,
                              hipStream_t stream) {
  const float* x  = (const float*)d_in[0];
  const float* rw = (const float*)d_in[1];
  const float* gw = (const float*)d_in[2];
  const float* uw = (const float*)d_in[3];
  const float* dw = (const float*)d_in[4];
  float* out = (float*)d_out;

  char* ws = (char*)d_ws;
  const size_t XB_OFF  = 0;
  const size_t TW_OFF  = XB_OFF + (size_t)T_TOK * HD * 2;
  const size_t CNT_OFF = TW_OFF + (size_t)T_TOK * TOPK * 4;
  const size_t LST_OFF = CNT_OFF + 256;
  const size_t HB_OFF  = LST_OFF + (size_t)NE * T_TOK * 4;

  unsigned short* xb  = (unsigned short*)(ws + XB_OFF);
  float*          tw  = (float*)(ws + TW_OFF);
  int*            cnt = (int*)(ws + CNT_OFF);
  int*            lst = (int*)(ws + LST_OFF);
  unsigned short* hb  = (unsigned short*)(ws + HB_OFF);

  hipMemsetAsync(cnt, 0, 256, stream);
  hipMemsetAsync(d_out, 0, (size_t)T_TOK * HD * sizeof(float), stream);

  router_kernel<<<T_TOK, 256, 0, stream>>>(x, rw, xb, tw, cnt, lst);
  gemm1_kernel<<<768, 512, 0, stream>>>(xb, gw, uw, cnt, lst, hb);
  gemm2_kernel<<<2048, 512, 0, stream>>>(hb, dw, cnt, lst, tw, out);
}